// Round 7
// baseline (161.557 us; speedup 1.0000x reference)
//
#include <hip/hip_runtime.h>

#define NROWS 8192
#define DDIM 512
#define ZROWS 16384
#define BM 256
#define BN 256
#define BK 64
#define KTILES (DDIM / BK)     // 8
#define NLR_BLOCKS 1024        // 32 x 32 (tm x lr-col-panel)
#define NSYM_BLOCKS 528        // upper triangle incl diag of 32
#define NBLOCKS (NLR_BLOCKS + NSYM_BLOCKS)   // 1552

typedef __attribute__((ext_vector_type(8))) short short8;
typedef __attribute__((ext_vector_type(4))) float f32x4;

__device__ __forceinline__ unsigned short f2bf(float f) {
  unsigned int u = __float_as_uint(f);
  u = (u + 0x7FFFu + ((u >> 16) & 1u)) >> 16;
  return (unsigned short)u;
}

// Kernel 1: per-row L2 normalize both inputs, write bf16 Z = [zl; zr],
// and compute the fp32 diagonal cosine sim dlr[i] = zl_i . zr_i.
__global__ __launch_bounds__(256) void nrm_kernel(const float* __restrict__ left,
                                                  const float* __restrict__ right,
                                                  unsigned short* __restrict__ Z,
                                                  float* __restrict__ dlr) {
  const int i = blockIdx.x;
  const int t = threadIdx.x;
  const float2 lv = ((const float2*)(left + (size_t)i * DDIM))[t];
  const float2 rv = ((const float2*)(right + (size_t)i * DDIM))[t];
  float ssl = lv.x * lv.x + lv.y * lv.y;
  float ssr = rv.x * rv.x + rv.y * rv.y;
  float slr = lv.x * rv.x + lv.y * rv.y;
#pragma unroll
  for (int m = 1; m < 64; m <<= 1) {
    ssl += __shfl_xor(ssl, m);
    ssr += __shfl_xor(ssr, m);
    slr += __shfl_xor(slr, m);
  }
  __shared__ float red[3][4];
  const int w = t >> 6;
  if ((t & 63) == 0) { red[0][w] = ssl; red[1][w] = ssr; red[2][w] = slr; }
  __syncthreads();
  ssl = red[0][0] + red[0][1] + red[0][2] + red[0][3];
  ssr = red[1][0] + red[1][1] + red[1][2] + red[1][3];
  slr = red[2][0] + red[2][1] + red[2][2] + red[2][3];
  const float invl = 1.0f / fmaxf(sqrtf(ssl), 1e-12f);
  const float invr = 1.0f / fmaxf(sqrtf(ssr), 1e-12f);
  if (t == 0) dlr[i] = slr * invl * invr;
  ushort2 zl2; zl2.x = f2bf(lv.x * invl); zl2.y = f2bf(lv.y * invl);
  ushort2 zr2; zr2.x = f2bf(rv.x * invr); zr2.y = f2bf(rv.y * invr);
  ((ushort2*)(Z + (size_t)i * DDIM))[t] = zl2;
  ((ushort2*)(Z + (size_t)(NROWS + i) * DDIM))[t] = zr2;
}

// Kernel 2: fused GEMM + exp-rowsum with ll-symmetry, 8-phase schedule,
// UNPINNED: no sched_barrier(0), no asm lgkmcnt in the loop — the compiler
// inserts fine-grained lgkmcnt for ds_read->MFMA deps and is free to
// interleave LDS reads with MFMA issue (the m141 lesson: order-pinning
// costs ~40%). Correctness anchors that remain: raw s_barrier pairs
// (publish/overwrite protocol for LDS buffers; side-effect ordering vs the
// global_load_lds intrinsics) and counted vmcnt(6) with "memory" clobber at
// P4/P8 (buffer-validity points; stop reads hoisting above validity).
//   read-last: A{j0,j2}@P1, B{all}@P1-P2, A{j1,j3}@P3 (per buffer)
//   stage:     p1:A13(kt+1) p2:A02(kt+2) p3:B01(kt+2) p4:B23(kt+2)
//              p5:A13(kt+2) p6:A02(kt+3) p7:B01(kt+3) p8:B23(kt+3)
//   vmcnt(6)@p4 => all <= p1's A13 landed (kt+1 complete for P5-P8 reads)
//   vmcnt(6)@p8 => all <= p5's A13 landed (kt+2 complete for next-P1 reads)
__global__ __launch_bounds__(512) void sim_kernel(const unsigned short* __restrict__ Z,
                                                  float* __restrict__ partial) {
  __shared__ __align__(16) unsigned short sA[2][BM * BK];   // 64 KiB
  __shared__ __align__(16) unsigned short sB[2][BN * BK];   // 64 KiB

  // ---- block decode
  int tm, tn; bool sym = false;
  {
    const int bid = blockIdx.x;
    if (bid < NLR_BLOCKS) {
      tm = bid >> 5; tn = 32 + (bid & 31);
    } else {
      const int b2 = bid - NLR_BLOCKS;            // 0..527
      int i = (int)(32.5f - sqrtf(32.5f * 32.5f - 2.0f * (float)b2));
      if (i < 0) i = 0; if (i > 31) i = 31;
      while (i > 0 && (32 * i - i * (i - 1) / 2) > b2) --i;
      while (i < 31 && (32 * (i + 1) - (i + 1) * i / 2) <= b2) ++i;
      tm = i; tn = i + (b2 - (32 * i - i * (i - 1) / 2));
      sym = (tn != tm);
    }
  }

  const int t = threadIdx.x;
  const int l = t & 63;
  const int w = t >> 6;        // wave 0..7
  const int wm = w >> 2;       // 0..1  (128-row slab)
  const int wn = w & 3;        // 0..3  (64-col slab)
  const int lr = l & 15;
  const int lk = l >> 4;       // 0..3

  f32x4 acc[8][4];
#pragma unroll
  for (int a = 0; a < 8; ++a)
#pragma unroll
    for (int b = 0; b < 4; ++b)
#pragma unroll
      for (int r = 0; r < 4; ++r) acc[a][b][r] = 0.0f;

  const unsigned short* Abase = Z + (size_t)tm * BM * DDIM;
  const unsigned short* Bbase = Z + (size_t)tn * BN * DDIM;

  // Staging: element e = j*512 + t; LDS slot-linear; global source slot
  // pre-swizzled by row&7; matching XOR on ds_read (verified conflict-free).
  const int srow = t >> 3;                       // 0..63
  const int scol = ((t & 7) ^ (srow & 7)) * 8;   // swizzled source element col

#define STAGE_AJ(bufi, k0, j)                                                     \
  __builtin_amdgcn_global_load_lds(                                               \
      (const __attribute__((address_space(1))) void*)(Abase +                     \
          (size_t)((j) * 64 + srow) * DDIM + (k0) + scol),                        \
      (__attribute__((address_space(3))) void*)(&sA[bufi][((j) * 512 + t) * 8]),  \
      16, 0, 0);
#define STAGE_BJ(bufi, k0, j)                                                     \
  __builtin_amdgcn_global_load_lds(                                               \
      (const __attribute__((address_space(1))) void*)(Bbase +                     \
          (size_t)((j) * 64 + srow) * DDIM + (k0) + scol),                        \
      (__attribute__((address_space(3))) void*)(&sB[bufi][((j) * 512 + t) * 8]),  \
      16, 0, 0);
#define STAGE_A02(b, k0) { STAGE_AJ(b, k0, 0) STAGE_AJ(b, k0, 2) }
#define STAGE_A13(b, k0) { STAGE_AJ(b, k0, 1) STAGE_AJ(b, k0, 3) }
#define STAGE_B01(b, k0) { STAGE_BJ(b, k0, 0) STAGE_BJ(b, k0, 1) }
#define STAGE_B23(b, k0) { STAGE_BJ(b, k0, 2) STAGE_BJ(b, k0, 3) }

  short8 af[4][2], ag[4][2], bf[4][2];

#define DS_A(dst, bufi, fmb)                                                       \
  _Pragma("unroll")                                                                \
  for (int fm = 0; fm < 4; ++fm)                                                   \
    _Pragma("unroll")                                                              \
    for (int ks = 0; ks < 2; ++ks) {                                               \
      const int row = wm * 128 + ((fmb) + fm) * 16 + lr;                           \
      dst[fm][ks] = *(const short8*)&sA[bufi][row * BK + ((ks * 4 + lk) ^ (lr & 7)) * 8]; \
    }

#define DS_B2(bufi, fnb)                                                           \
  _Pragma("unroll")                                                                \
  for (int fn = 0; fn < 2; ++fn)                                                   \
    _Pragma("unroll")                                                              \
    for (int ks = 0; ks < 2; ++ks) {                                               \
      const int row = wn * 64 + ((fnb) + fn) * 16 + lr;                            \
      bf[(fnb) + fn][ks] = *(const short8*)&sB[bufi][row * BK + ((ks * 4 + lk) ^ (lr & 7)) * 8]; \
    }

#define MFMA16(A, fmb, fnb)                                                        \
  __builtin_amdgcn_s_setprio(1);                                                   \
  _Pragma("unroll")                                                                \
  for (int fm = 0; fm < 4; ++fm)                                                   \
    _Pragma("unroll")                                                              \
    for (int fn = 0; fn < 2; ++fn)                                                 \
      _Pragma("unroll")                                                            \
      for (int ks = 0; ks < 2; ++ks)                                               \
        acc[(fmb) + fm][(fnb) + fn] =                                              \
            __builtin_amdgcn_mfma_f32_16x16x32_bf16(A[fm][ks], bf[(fnb) + fn][ks], \
                                                    acc[(fmb) + fm][(fnb) + fn],   \
                                                    0, 0, 0);                      \
  __builtin_amdgcn_s_setprio(0);

#define BAR   __builtin_amdgcn_s_barrier()
#define VM6   asm volatile("s_waitcnt vmcnt(6)" ::: "memory")
#define VM0   asm volatile("s_waitcnt vmcnt(0)" ::: "memory")

  // prologue: kt0 fully + kt1 {A02,B01,B23}; vmcnt(6) leaves kt1's 3 pairs
  // in flight, guarantees kt0 landed.
  STAGE_A02(0, 0); STAGE_A13(0, 0); STAGE_B01(0, 0); STAGE_B23(0, 0);
  STAGE_A02(1, BK); STAGE_B01(1, BK); STAGE_B23(1, BK);
  VM6;
  BAR;

#pragma unroll
  for (int it = 0; it < 4; ++it) {
    const int kt = 2 * it;
    // ---- P1: (M0,N0) buf0 | stage A13(kt+1)->buf1
    DS_A(af, 0, 0); DS_B2(0, 0);
    STAGE_A13(1, (kt + 1) * BK);
    BAR;
    MFMA16(af, 0, 0);
    BAR;
    // ---- P2: (M0,N1) buf0 | stage A02(kt+2)->buf0
    DS_B2(0, 2);
    if (kt + 2 < KTILES) STAGE_A02(0, (kt + 2) * BK);
    BAR;
    MFMA16(af, 0, 2);
    BAR;
    // ---- P3: (M1,N0) buf0 | stage B01(kt+2)->buf0
    DS_A(ag, 0, 4);
    if (kt + 2 < KTILES) STAGE_B01(0, (kt + 2) * BK);
    BAR;
    MFMA16(ag, 4, 0);
    BAR;
    // ---- P4: (M1,N1) buf0 | stage B23(kt+2)->buf0 | counted vmcnt
    if (kt + 2 < KTILES) { STAGE_B23(0, (kt + 2) * BK); VM6; } else { VM0; }
    BAR;
    MFMA16(ag, 4, 2);
    BAR;
    // ---- P5: (M0,N0) buf1 | stage A13(kt+2)->buf0
    DS_A(af, 1, 0); DS_B2(1, 0);
    if (kt + 2 < KTILES) STAGE_A13(0, (kt + 2) * BK);
    BAR;
    MFMA16(af, 0, 0);
    BAR;
    // ---- P6: (M0,N1) buf1 | stage A02(kt+3)->buf1
    DS_B2(1, 2);
    if (kt + 3 < KTILES) STAGE_A02(1, (kt + 3) * BK);
    BAR;
    MFMA16(af, 0, 2);
    BAR;
    // ---- P7: (M1,N0) buf1 | stage B01(kt+3)->buf1
    DS_A(ag, 1, 4);
    if (kt + 3 < KTILES) STAGE_B01(1, (kt + 3) * BK);
    BAR;
    MFMA16(ag, 4, 0);
    BAR;
    // ---- P8: (M1,N1) buf1 | stage B23(kt+3)->buf1 | counted vmcnt
    if (kt + 3 < KTILES) { STAGE_B23(1, (kt + 3) * BK); VM6; } else { VM0; }
    BAR;
    MFMA16(ag, 4, 2);
    BAR;
  }

  // ---- Epilogue: e = exp(2*s); rowsums always, colsums when sym.
  // C/D layout (16x16x32): col = lane&15, row = (lane>>4)*4 + reg.
  // All DMA drained (VM0 at it=3 P4/P8); sA[0] is dead -> overlay reductions.
  float* rsum = (float*)&sA[0][0];        // 256 floats
  float* csum = rsum + BM;                // 256 floats
  if (t < BM) { rsum[t] = 0.0f; csum[t] = 0.0f; }
  __syncthreads();
  float c0 = 0.0f, c1 = 0.0f, c2 = 0.0f, c3 = 0.0f;
#pragma unroll
  for (int fm = 0; fm < 8; ++fm) {
#pragma unroll
    for (int r = 0; r < 4; ++r) {
      float e0 = __expf(2.0f * acc[fm][0][r]);
      float e1 = __expf(2.0f * acc[fm][1][r]);
      float e2 = __expf(2.0f * acc[fm][2][r]);
      float e3 = __expf(2.0f * acc[fm][3][r]);
      float v = e0 + e1 + e2 + e3;
      v += __shfl_xor(v, 1);
      v += __shfl_xor(v, 2);
      v += __shfl_xor(v, 4);
      v += __shfl_xor(v, 8);
      if (lr == 0) atomicAdd(&rsum[wm * 128 + fm * 16 + lk * 4 + r], v);
      c0 += e0; c1 += e1; c2 += e2; c3 += e3;
    }
  }
  if (sym) {
    c0 += __shfl_xor(c0, 16); c0 += __shfl_xor(c0, 32);
    c1 += __shfl_xor(c1, 16); c1 += __shfl_xor(c1, 32);
    c2 += __shfl_xor(c2, 16); c2 += __shfl_xor(c2, 32);
    c3 += __shfl_xor(c3, 16); c3 += __shfl_xor(c3, 32);
    if (l < 16) {   // one lane per column per wave; 2 waves (wm) share a col
      atomicAdd(&csum[wn * 64 +  0 + lr], c0);
      atomicAdd(&csum[wn * 64 + 16 + lr], c1);
      atomicAdd(&csum[wn * 64 + 32 + lr], c2);
      atomicAdd(&csum[wn * 64 + 48 + lr], c3);
    }
  }
  __syncthreads();
  if (t < BM) partial[(size_t)tn * NROWS + tm * BM + t] = rsum[t];
  if (sym && t < BM) partial[(size_t)tm * NROWS + tn * BM + t] = csum[t];
}

// Kernel 3: reduce partials, final loss.
// loss[i] = log(rowsum - e^2) - 2*dlr[i]
__global__ __launch_bounds__(256) void fin_kernel(const float* __restrict__ partial,
                                                  const float* __restrict__ dlr,
                                                  float* __restrict__ out) {
  const int i = blockIdx.x * 256 + threadIdx.x;
  float s = 0.0f;
#pragma unroll 8
  for (int p = 0; p < 64; ++p) s += partial[(size_t)p * NROWS + i];
  out[i] = logf(s - 7.38905609893065f) - 2.0f * dlr[i];
}

extern "C" void kernel_launch(void* const* d_in, const int* in_sizes, int n_in,
                              void* d_out, int out_size, void* d_ws, size_t ws_size,
                              hipStream_t stream) {
  const float* left = (const float*)d_in[0];
  const float* right = (const float*)d_in[1];
  float* out = (float*)d_out;

  unsigned short* Z = (unsigned short*)d_ws;                       // 16 MB
  char* p = (char*)d_ws + (size_t)ZROWS * DDIM * 2;
  float* dlr = (float*)p;                                          // 32 KB
  float* partial = (float*)(p + (size_t)NROWS * 4);                // 2 MB

  nrm_kernel<<<NROWS, 256, 0, stream>>>(left, right, Z, dlr);
  sim_kernel<<<NBLOCKS, 512, 0, stream>>>(Z, partial);
  fin_kernel<<<NROWS / 256, 256, 0, stream>>>(partial, dlr, out);
}

// Round 8
// 157.383 us; speedup vs baseline: 1.0265x; 1.0265x over previous
//
#include <hip/hip_runtime.h>

#define NROWS 8192
#define DDIM 512
#define ZROWS 16384
#define BM 256
#define BN 256
#define BK 64
#define KTILES 8
#define NLR_TILES 1024         // 32 x 32 (tm x lr-col-panel)
#define NTILES 1552            // + 528 upper-triangle ll tiles
#define GRID 256               // persistent: 1 block/CU

typedef __attribute__((ext_vector_type(8))) short short8;
typedef __attribute__((ext_vector_type(4))) float f32x4;

__device__ __forceinline__ unsigned short f2bf(float f) {
  unsigned int u = __float_as_uint(f);
  u = (u + 0x7FFFu + ((u >> 16) & 1u)) >> 16;
  return (unsigned short)u;
}

__device__ __forceinline__ void decode_tile(int tile, int& tm, int& tn, bool& sym) {
  if (tile < NLR_TILES) {
    tm = tile >> 5; tn = 32 + (tile & 31); sym = false;
  } else {
    const int b2 = tile - NLR_TILES;            // 0..527
    int i = (int)(32.5f - sqrtf(32.5f * 32.5f - 2.0f * (float)b2));
    if (i < 0) i = 0; if (i > 31) i = 31;
    while (i > 0 && (32 * i - i * (i - 1) / 2) > b2) --i;
    while (i < 31 && (32 * (i + 1) - (i + 1) * i / 2) <= b2) ++i;
    tm = i; tn = i + (b2 - (32 * i - i * (i - 1) / 2));
    sym = (tn != tm);
  }
}

// Kernel 1: per-row L2 normalize both inputs, write bf16 Z = [zl; zr],
// and compute the fp32 diagonal cosine sim dlr[i] = zl_i . zr_i.
__global__ __launch_bounds__(256) void nrm_kernel(const float* __restrict__ left,
                                                  const float* __restrict__ right,
                                                  unsigned short* __restrict__ Z,
                                                  float* __restrict__ dlr) {
  const int i = blockIdx.x;
  const int t = threadIdx.x;
  const float2 lv = ((const float2*)(left + (size_t)i * DDIM))[t];
  const float2 rv = ((const float2*)(right + (size_t)i * DDIM))[t];
  float ssl = lv.x * lv.x + lv.y * lv.y;
  float ssr = rv.x * rv.x + rv.y * rv.y;
  float slr = lv.x * rv.x + lv.y * rv.y;
#pragma unroll
  for (int m = 1; m < 64; m <<= 1) {
    ssl += __shfl_xor(ssl, m);
    ssr += __shfl_xor(ssr, m);
    slr += __shfl_xor(slr, m);
  }
  __shared__ float red[3][4];
  const int w = t >> 6;
  if ((t & 63) == 0) { red[0][w] = ssl; red[1][w] = ssr; red[2][w] = slr; }
  __syncthreads();
  ssl = red[0][0] + red[0][1] + red[0][2] + red[0][3];
  ssr = red[1][0] + red[1][1] + red[1][2] + red[1][3];
  slr = red[2][0] + red[2][1] + red[2][2] + red[2][3];
  const float invl = 1.0f / fmaxf(sqrtf(ssl), 1e-12f);
  const float invr = 1.0f / fmaxf(sqrtf(ssr), 1e-12f);
  if (t == 0) dlr[i] = slr * invl * invr;
  ushort2 zl2; zl2.x = f2bf(lv.x * invl); zl2.y = f2bf(lv.y * invl);
  ushort2 zr2; zr2.x = f2bf(rv.x * invr); zr2.y = f2bf(rv.y * invr);
  ((ushort2*)(Z + (size_t)i * DDIM))[t] = zl2;
  ((ushort2*)(Z + (size_t)(NROWS + i) * DDIM))[t] = zr2;
}

// Kernel 2: PERSISTENT fused GEMM + exp-rowsum with ll-symmetry.
// 256 blocks (1/CU); block b owns tiles b, b+256, ... Seamless cross-tile
// pipeline: the per-phase half-tile staging stream continues into the next
// tile's kt0/kt1 (base-pointer switch only); counted vmcnt(6) throughout,
// NO drain between tiles. Epilogue uses dedicated LDS (rsum/csum) and raw
// s_barrier + lgkmcnt(0) only (no __syncthreads -> no vmcnt(0) drain of the
// cross-tile prefetch). Per-tile K-loop rolled (#pragma unroll 1).
//   read-last (per buffer): A{j0,j2}@P1/P5, B{all}@P1-P2/P5-P6, A{j1,j3}@P3/P7
//   stage: p1:A13(k+1) p2:A02(k+2) p3:B01(k+2) p4:B23(k+2)+VM6
//          p5:A13(k+2) p6:A02(k+3) p7:B01(k+3) p8:B23(k+3)+VM6
//   where k+2/k+3 >= 8 map to next tile's kt0/kt1.
__global__ __launch_bounds__(512) void sim_kernel(const unsigned short* __restrict__ Z,
                                                  float* __restrict__ partial) {
  __shared__ __align__(16) unsigned short sA[2][BM * BK];   // 64 KiB
  __shared__ __align__(16) unsigned short sB[2][BN * BK];   // 64 KiB
  __shared__ float rsum[BM];
  __shared__ float csum[BM];

  const int t = threadIdx.x;
  const int l = t & 63;
  const int w = t >> 6;        // wave 0..7
  const int wm = w >> 2;       // 0..1  (128-row slab)
  const int wn = w & 3;        // 0..3  (64-col slab)
  const int lr = l & 15;
  const int lk = l >> 4;       // 0..3
  const int srow = t >> 3;                       // 0..63
  const int scol = ((t & 7) ^ (srow & 7)) * 8;   // swizzled source element col

  int tile = blockIdx.x;
  int tm, tn; bool sym;
  decode_tile(tile, tm, tn, sym);
  const unsigned short* Abase = Z + (size_t)tm * BM * DDIM;
  const unsigned short* Bbase = Z + (size_t)tn * BN * DDIM;

#define GLDA(bufi, gbase, k0, j)                                                  \
  __builtin_amdgcn_global_load_lds(                                               \
      (const __attribute__((address_space(1))) void*)((gbase) +                   \
          (size_t)((j) * 64 + srow) * DDIM + (k0) + scol),                        \
      (__attribute__((address_space(3))) void*)(&sA[bufi][((j) * 512 + t) * 8]),  \
      16, 0, 0);
#define GLDB(bufi, gbase, k0, j)                                                  \
  __builtin_amdgcn_global_load_lds(                                               \
      (const __attribute__((address_space(1))) void*)((gbase) +                   \
          (size_t)((j) * 64 + srow) * DDIM + (k0) + scol),                        \
      (__attribute__((address_space(3))) void*)(&sB[bufi][((j) * 512 + t) * 8]),  \
      16, 0, 0);
#define STAGE_A02g(b, g, k) { GLDA(b, g, k, 0) GLDA(b, g, k, 2) }
#define STAGE_A13g(b, g, k) { GLDA(b, g, k, 1) GLDA(b, g, k, 3) }
#define STAGE_B01g(b, g, k) { GLDB(b, g, k, 0) GLDB(b, g, k, 1) }
#define STAGE_B23g(b, g, k) { GLDB(b, g, k, 2) GLDB(b, g, k, 3) }

#define DS_A(dst, bufi, fmb)                                                       \
  _Pragma("unroll")                                                                \
  for (int fm = 0; fm < 4; ++fm)                                                   \
    _Pragma("unroll")                                                              \
    for (int ks = 0; ks < 2; ++ks) {                                               \
      const int row = wm * 128 + ((fmb) + fm) * 16 + lr;                           \
      dst[fm][ks] = *(const short8*)&sA[bufi][row * BK + ((ks * 4 + lk) ^ (lr & 7)) * 8]; \
    }

#define DS_B2(bufi, fnb)                                                           \
  _Pragma("unroll")                                                                \
  for (int fn = 0; fn < 2; ++fn)                                                   \
    _Pragma("unroll")                                                              \
    for (int ks = 0; ks < 2; ++ks) {                                               \
      const int row = wn * 64 + ((fnb) + fn) * 16 + lr;                            \
      bf[(fnb) + fn][ks] = *(const short8*)&sB[bufi][row * BK + ((ks * 4 + lk) ^ (lr & 7)) * 8]; \
    }

#define MFMA16(A, fmb, fnb)                                                        \
  __builtin_amdgcn_s_setprio(1);                                                   \
  _Pragma("unroll")                                                                \
  for (int fm = 0; fm < 4; ++fm)                                                   \
    _Pragma("unroll")                                                              \
    for (int fn = 0; fn < 2; ++fn)                                                 \
      _Pragma("unroll")                                                            \
      for (int ks = 0; ks < 2; ++ks)                                               \
        acc[(fmb) + fm][(fnb) + fn] =                                              \
            __builtin_amdgcn_mfma_f32_16x16x32_bf16(A[fm][ks], bf[(fnb) + fn][ks], \
                                                    acc[(fmb) + fm][(fnb) + fn],   \
                                                    0, 0, 0);                      \
  __builtin_amdgcn_s_setprio(0);

#define BAR   __builtin_amdgcn_s_barrier()
#define VM6   asm volatile("s_waitcnt vmcnt(6)" ::: "memory")
#define VM0   asm volatile("s_waitcnt vmcnt(0)" ::: "memory")
#define LGKM0_BAR { asm volatile("s_waitcnt lgkmcnt(0)" ::: "memory"); BAR; }

  // prologue: tile0 kt0 full -> buf0, kt1 {A02,B01,B23} -> buf1 (14 pairs);
  // VM6 (<=6 instrs outstanding) => kt0's 8 landed, kt1's 3 pairs in flight.
  STAGE_A02g(0, Abase, 0); STAGE_A13g(0, Abase, 0);
  STAGE_B01g(0, Bbase, 0); STAGE_B23g(0, Bbase, 0);
  STAGE_A02g(1, Abase, BK); STAGE_B01g(1, Bbase, BK); STAGE_B23g(1, Bbase, BK);
  VM6;
  BAR;

  while (true) {
    const int tileN = tile + GRID;
    const bool has_next = (tileN < NTILES);
    int tmN = tm, tnN = tn; bool symN = false;
    if (has_next) decode_tile(tileN, tmN, tnN, symN);
    const unsigned short* AbaseN = Z + (size_t)tmN * BM * DDIM;
    const unsigned short* BbaseN = Z + (size_t)tnN * BN * DDIM;

    f32x4 acc[8][4];
#pragma unroll
    for (int a = 0; a < 8; ++a)
#pragma unroll
      for (int b = 0; b < 4; ++b)
#pragma unroll
        for (int r = 0; r < 4; ++r) acc[a][b][r] = 0.0f;

    short8 af[4][2], ag[4][2], bf[4][2];

#pragma unroll 1
    for (int it = 0; it < 4; ++it) {
      const int k2 = 2 * it + 2, k3 = 2 * it + 3;
      const bool st2 = (k2 < KTILES) || has_next;
      const bool st3 = (k3 < KTILES) || has_next;
      const unsigned short* A2 = (k2 < KTILES) ? Abase : AbaseN;
      const unsigned short* B2 = (k2 < KTILES) ? Bbase : BbaseN;
      const unsigned short* A3 = (k3 < KTILES) ? Abase : AbaseN;
      const unsigned short* B3 = (k3 < KTILES) ? Bbase : BbaseN;
      const int k2o = (k2 & 7) * BK;
      const int k3o = (k3 & 7) * BK;
      const int k1o = (2 * it + 1) * BK;

      // ---- P1: (M0,N0) buf0 | stage A13(kt+1)->buf1
      DS_A(af, 0, 0); DS_B2(0, 0);
      STAGE_A13g(1, Abase, k1o);
      BAR; MFMA16(af, 0, 0); BAR;
      // ---- P2: (M0,N1) buf0 | stage A02(k2)->buf0
      DS_B2(0, 2);
      if (st2) STAGE_A02g(0, A2, k2o);
      BAR; MFMA16(af, 0, 2); BAR;
      // ---- P3: (M1,N0) buf0 | stage B01(k2)->buf0
      DS_A(ag, 0, 4);
      if (st2) STAGE_B01g(0, B2, k2o);
      BAR; MFMA16(ag, 4, 0); BAR;
      // ---- P4: (M1,N1) buf0 | stage B23(k2)->buf0 | counted vmcnt
      if (st2) { STAGE_B23g(0, B2, k2o); VM6; } else { VM0; }
      BAR; MFMA16(ag, 4, 2); BAR;
      // ---- P5: (M0,N0) buf1 | stage A13(k2)->buf0
      DS_A(af, 1, 0); DS_B2(1, 0);
      if (st2) STAGE_A13g(0, A2, k2o);
      BAR; MFMA16(af, 0, 0); BAR;
      // ---- P6: (M0,N1) buf1 | stage A02(k3)->buf1
      DS_B2(1, 2);
      if (st3) STAGE_A02g(1, A3, k3o);
      BAR; MFMA16(af, 0, 2); BAR;
      // ---- P7: (M1,N0) buf1 | stage B01(k3)->buf1
      DS_A(ag, 1, 4);
      if (st3) STAGE_B01g(1, B3, k3o);
      BAR; MFMA16(ag, 4, 0); BAR;
      // ---- P8: (M1,N1) buf1 | stage B23(k3)->buf1 | counted vmcnt
      if (st3) { STAGE_B23g(1, B3, k3o); VM6; } else { VM0; }
      BAR; MFMA16(ag, 4, 2); BAR;
    }

    // ---- Epilogue: e = exp(2*s); rowsums always, colsums when sym.
    // Dedicated LDS; raw barriers + lgkmcnt only (keep cross-tile DMA alive).
    if (t < BM) { rsum[t] = 0.0f; csum[t] = 0.0f; }
    LGKM0_BAR;
    float c0 = 0.0f, c1 = 0.0f, c2 = 0.0f, c3 = 0.0f;
#pragma unroll
    for (int fm = 0; fm < 8; ++fm) {
#pragma unroll
      for (int r = 0; r < 4; ++r) {
        float e0 = __expf(2.0f * acc[fm][0][r]);
        float e1 = __expf(2.0f * acc[fm][1][r]);
        float e2 = __expf(2.0f * acc[fm][2][r]);
        float e3 = __expf(2.0f * acc[fm][3][r]);
        float v = e0 + e1 + e2 + e3;
        v += __shfl_xor(v, 1);
        v += __shfl_xor(v, 2);
        v += __shfl_xor(v, 4);
        v += __shfl_xor(v, 8);
        if (lr == 0) atomicAdd(&rsum[wm * 128 + fm * 16 + lk * 4 + r], v);
        c0 += e0; c1 += e1; c2 += e2; c3 += e3;
      }
    }
    if (sym) {
      c0 += __shfl_xor(c0, 16); c0 += __shfl_xor(c0, 32);
      c1 += __shfl_xor(c1, 16); c1 += __shfl_xor(c1, 32);
      c2 += __shfl_xor(c2, 16); c2 += __shfl_xor(c2, 32);
      c3 += __shfl_xor(c3, 16); c3 += __shfl_xor(c3, 32);
      if (l < 16) {   // one lane per column per wave; 2 waves (wm) share a col
        atomicAdd(&csum[wn * 64 +  0 + lr], c0);
        atomicAdd(&csum[wn * 64 + 16 + lr], c1);
        atomicAdd(&csum[wn * 64 + 32 + lr], c2);
        atomicAdd(&csum[wn * 64 + 48 + lr], c3);
      }
    }
    LGKM0_BAR;
    if (t < BM) partial[(size_t)tn * NROWS + tm * BM + t] = rsum[t];
    if (sym && t < BM) partial[(size_t)tm * NROWS + tn * BM + t] = csum[t];

    if (!has_next) break;
    tile = tileN; tm = tmN; tn = tnN; sym = symN; Abase = AbaseN; Bbase = BbaseN;
  }
}

// Kernel 3: reduce partials, final loss.
// loss[i] = log(rowsum - e^2) - 2*dlr[i]
__global__ __launch_bounds__(256) void fin_kernel(const float* __restrict__ partial,
                                                  const float* __restrict__ dlr,
                                                  float* __restrict__ out) {
  const int i = blockIdx.x * 256 + threadIdx.x;
  float s = 0.0f;
#pragma unroll 8
  for (int p = 0; p < 64; ++p) s += partial[(size_t)p * NROWS + i];
  out[i] = logf(s - 7.38905609893065f) - 2.0f * dlr[i];
}

extern "C" void kernel_launch(void* const* d_in, const int* in_sizes, int n_in,
                              void* d_out, int out_size, void* d_ws, size_t ws_size,
                              hipStream_t stream) {
  const float* left = (const float*)d_in[0];
  const float* right = (const float*)d_in[1];
  float* out = (float*)d_out;

  unsigned short* Z = (unsigned short*)d_ws;                       // 16 MB
  char* p = (char*)d_ws + (size_t)ZROWS * DDIM * 2;
  float* dlr = (float*)p;                                          // 32 KB
  float* partial = (float*)(p + (size_t)NROWS * 4);                // 2 MB

  nrm_kernel<<<NROWS, 256, 0, stream>>>(left, right, Z, dlr);
  sim_kernel<<<GRID, 512, 0, stream>>>(Z, partial);
  fin_kernel<<<NROWS / 256, 256, 0, stream>>>(partial, dlr, out);
}